// Round 1
// baseline (3785.183 us; speedup 1.0000x reference)
//
#include <hip/hip_runtime.h>
#include <math.h>

#define B_    2048
#define LC    20
#define LQ    50
#define CTX   2048
#define CTXM  512
#define NEGV  -1e30f

// ---------------- Kernel 1: per-row scale = g[m] / ||trans_v[m,:]|| ----------------
__global__ __launch_bounds__(256)
void scale_kernel(const float* __restrict__ trans_v,
                  const float* __restrict__ trans_g,
                  float* __restrict__ scale) {
    int m = blockIdx.x;
    int t = threadIdx.x;
    const float* row = trans_v + (size_t)m * CTX;
    float ss = 0.f;
    for (int i = t; i < CTX; i += 256) { float v = row[i]; ss += v * v; }
    __shared__ float red[256];
    red[t] = ss;
    __syncthreads();
    for (int s = 128; s > 0; s >>= 1) {
        if (t < s) red[t] += red[t + s];
        __syncthreads();
    }
    if (t == 0) scale[m] = trans_g[m] / sqrtf(red[0]);
}

// ---------------- Kernel 2: V = Vid(40960x2048) @ (scale*trans_v)^T + trans_b ----------------
#define BM 128
#define BN 128
#define BK 32

__global__ __launch_bounds__(256)
void gemm_kernel(const float* __restrict__ A,        // (40960, 2048)
                 const float* __restrict__ Wt,       // (512, 2048) = trans_v
                 const float* __restrict__ scale,    // (512)
                 const float* __restrict__ trans_b,  // (512)
                 float* __restrict__ V)              // (40960, 512)
{
    __shared__ float As[BK][BM + 4];
    __shared__ float Bs[BK][BN + 4];
    __shared__ float sc[BN];

    int t  = threadIdx.x;
    int n0 = blockIdx.x * BN;
    int m0 = blockIdx.y * BM;
    int tx = t & 15, ty = t >> 4;

    if (t < BN) sc[t] = scale[n0 + t];

    float acc[8][8];
#pragma unroll
    for (int i = 0; i < 8; i++)
#pragma unroll
        for (int j = 0; j < 8; j++) acc[i][j] = 0.f;

    __syncthreads();

    for (int k0 = 0; k0 < CTX; k0 += BK) {
        // stage A tile (transposed into As[k][m])
#pragma unroll
        for (int i = 0; i < 4; ++i) {
            int f4 = t + i * 256;            // 0..1023
            int r  = f4 >> 3;                // row in tile
            int kc = (f4 & 7) << 2;          // k offset (x4)
            const float4 v = *reinterpret_cast<const float4*>(
                &A[(size_t)(m0 + r) * CTX + k0 + kc]);
            As[kc + 0][r] = v.x; As[kc + 1][r] = v.y;
            As[kc + 2][r] = v.z; As[kc + 3][r] = v.w;
        }
        // stage B tile (scaled, transposed into Bs[k][n])
#pragma unroll
        for (int i = 0; i < 4; ++i) {
            int f4 = t + i * 256;
            int r  = f4 >> 3;
            int kc = (f4 & 7) << 2;
            float s = sc[r];
            const float4 v = *reinterpret_cast<const float4*>(
                &Wt[(size_t)(n0 + r) * CTX + k0 + kc]);
            Bs[kc + 0][r] = v.x * s; Bs[kc + 1][r] = v.y * s;
            Bs[kc + 2][r] = v.z * s; Bs[kc + 3][r] = v.w * s;
        }
        __syncthreads();
#pragma unroll
        for (int kk = 0; kk < BK; ++kk) {
            float a[8], b[8];
            *(float4*)&a[0] = *(const float4*)&As[kk][ty * 8];
            *(float4*)&a[4] = *(const float4*)&As[kk][ty * 8 + 4];
            *(float4*)&b[0] = *(const float4*)&Bs[kk][tx * 8];
            *(float4*)&b[4] = *(const float4*)&Bs[kk][tx * 8 + 4];
#pragma unroll
            for (int i = 0; i < 8; i++)
#pragma unroll
                for (int j = 0; j < 8; j++)
                    acc[i][j] = fmaf(a[i], b[j], acc[i][j]);
        }
        __syncthreads();
    }

    // epilogue: add trans_b, store
#pragma unroll
    for (int i = 0; i < 8; i++) {
        size_t m = (size_t)(m0 + ty * 8 + i);
#pragma unroll
        for (int j0 = 0; j0 < 8; j0 += 4) {
            int n = n0 + tx * 8 + j0;
            float4 o;
            o.x = acc[i][j0 + 0] + trans_b[n + 0];
            o.y = acc[i][j0 + 1] + trans_b[n + 1];
            o.z = acc[i][j0 + 2] + trans_b[n + 2];
            o.w = acc[i][j0 + 3] + trans_b[n + 3];
            *reinterpret_cast<float4*>(&V[m * CTXM + n]) = o;
        }
    }
}

// ---------------- Kernel 3: per-batch attention + epilogue ----------------
#define QCH 16

__global__ __launch_bounds__(256)
void attn_kernel(const float* __restrict__ Ques,    // (B, 512, 50)
                 const float* __restrict__ V_mask,  // (B, 20)
                 const float* __restrict__ Q_mask,  // (B, 50)
                 const float* __restrict__ w4V,     // (512)
                 const float* __restrict__ w4Q,     // (512)
                 const float* __restrict__ w4mlu,   // (512)
                 const float* __restrict__ bias,    // (1)
                 const float* __restrict__ V,       // (B*20, 512)
                 float* __restrict__ out)           // (B, 2048, 20)
{
    __shared__ float Vsh[LC][CTXM];     // 40 KB
    __shared__ float wmsh[CTXM];
    __shared__ float Qc[QCH][LQ + 2];
    __shared__ float Ssh[LC][LQ];
    __shared__ float S1sh[LC][LQ];
    __shared__ float S2sh[LC][LQ];
    __shared__ float Btsh[LC][LC];
    __shared__ float s0sh[LC];
    __shared__ float s1qsh[LQ];
    __shared__ float s0p[LC][8];
    __shared__ float qmsh[LQ];
    __shared__ float vmsh[LC];

    int b = blockIdx.x;
    int t = threadIdx.x;
    const float* Vb = V + (size_t)b * (LC * CTXM);
    const float* Qb = Ques + (size_t)b * (CTXM * LQ);

    // stage V (20x512 = 2560 float4)
    {
        const float4* src = reinterpret_cast<const float4*>(Vb);
        float4* dst = reinterpret_cast<float4*>(&Vsh[0][0]);
#pragma unroll
        for (int i = 0; i < 10; i++) dst[t + i * 256] = src[t + i * 256];
    }
    for (int i = t; i < CTXM; i += 256) wmsh[i] = w4mlu[i];
    if (t < LQ) qmsh[t] = Q_mask[(size_t)b * LQ + t];
    if (t < LC) vmsh[t] = V_mask[(size_t)b * LC + t];
    __syncthreads();

    // s0[l] = sum_d V[l,d]*w4V[d]  (8 partial lanes per l)
    if (t < LC * 8) {
        int l = t >> 3, lane = t & 7;
        float acc = 0.f;
        for (int d = lane; d < CTXM; d += 8) acc += Vsh[l][d] * w4V[d];
        s0p[l][lane] = acc;
    }
    __syncthreads();
    if (t < LC) {
        float s = 0.f;
#pragma unroll
        for (int i = 0; i < 8; i++) s += s0p[t][i];
        s0sh[t] = s;
    }

    // chunked loop over d: s2 (per-thread 4 l's x 1 q) and s1
    float acc2[4] = {0.f, 0.f, 0.f, 0.f};
    int q  = t % LQ;          // valid for t < 250
    int l0 = (t / LQ) * 4;
    float s1acc = 0.f;
    for (int c0 = 0; c0 < CTXM; c0 += QCH) {
        __syncthreads();
        for (int i = t; i < QCH * LQ; i += 256) {
            int dd = i / LQ, qq = i % LQ;
            Qc[dd][qq] = Qb[(size_t)(c0 + dd) * LQ + qq];
        }
        __syncthreads();
        if (t < 250) {
#pragma unroll
            for (int dd = 0; dd < QCH; ++dd) {
                float wq = wmsh[c0 + dd] * Qc[dd][q];
                acc2[0] = fmaf(Vsh[l0 + 0][c0 + dd], wq, acc2[0]);
                acc2[1] = fmaf(Vsh[l0 + 1][c0 + dd], wq, acc2[1]);
                acc2[2] = fmaf(Vsh[l0 + 2][c0 + dd], wq, acc2[2]);
                acc2[3] = fmaf(Vsh[l0 + 3][c0 + dd], wq, acc2[3]);
            }
        }
        if (t < LQ) {
#pragma unroll
            for (int dd = 0; dd < QCH; ++dd)
                s1acc = fmaf(Qc[dd][t], w4Q[c0 + dd], s1acc);
        }
    }
    if (t < LQ) s1qsh[t] = s1acc;
    __syncthreads();

    // S = s0 + s1 + s2 + bias
    if (t < 250) {
        float bb = bias[0];
#pragma unroll
        for (int i = 0; i < 4; i++)
            Ssh[l0 + i][q] = acc2[i] + s0sh[l0 + i] + s1qsh[q] + bb;
    }
    __syncthreads();

    // S1: softmax over q (rows), wave 0; S2: softmax over l (cols), wave 1
    if (t < LC) {
        int l = t;
        float mx = -INFINITY;
        for (int j = 0; j < LQ; j++) {
            float qm = qmsh[j];
            float x = Ssh[l][j] * qm + (1.f - qm) * NEGV;
            mx = fmaxf(mx, x);
        }
        float sum = 0.f;
        for (int j = 0; j < LQ; j++) {
            float qm = qmsh[j];
            float x = Ssh[l][j] * qm + (1.f - qm) * NEGV;
            float e = expf(x - mx);
            S1sh[l][j] = e;
            sum += e;
        }
        float inv = 1.f / sum;
        for (int j = 0; j < LQ; j++) S1sh[l][j] *= inv;
    } else if (t >= 64 && t < 64 + LQ) {
        int j = t - 64;
        float mx = -INFINITY;
        for (int l = 0; l < LC; l++) {
            float vm = vmsh[l];
            float x = Ssh[l][j] * vm + (1.f - vm) * NEGV;
            mx = fmaxf(mx, x);
        }
        float sum = 0.f;
        for (int l = 0; l < LC; l++) {
            float vm = vmsh[l];
            float x = Ssh[l][j] * vm + (1.f - vm) * NEGV;
            float e = expf(x - mx);
            S2sh[l][j] = e;
            sum += e;
        }
        float inv = 1.f / sum;
        for (int l = 0; l < LC; l++) S2sh[l][j] *= inv;
    }
    __syncthreads();

    // Bt[l][m] = sum_q S1[l,q]*S2[m,q]
    for (int p = t; p < LC * LC; p += 256) {
        int l = p / LC, m = p % LC;
        float s = 0.f;
        for (int j = 0; j < LQ; j++) s += S1sh[l][j] * S2sh[m][j];
        Btsh[l][m] = s;
    }
    __syncthreads();

    // per-d epilogue: A[l,d], Bv[l,d], write V|A|V*A|V*Bv transposed
    float* outb = out + (size_t)b * (4 * CTXM * LC);
#pragma unroll
    for (int h = 0; h < 2; ++h) {
        int d = t + h * 256;
        float qrow[LQ];
        const float* qr = Qb + (size_t)d * LQ;
#pragma unroll
        for (int j = 0; j < LQ; j += 2) {
            float2 v = *reinterpret_cast<const float2*>(&qr[j]);
            qrow[j] = v.x; qrow[j + 1] = v.y;
        }
        float av[LC], bv[LC], vv[LC];
#pragma unroll
        for (int l = 0; l < LC; l++) {
            float a = 0.f;
#pragma unroll
            for (int j = 0; j < LQ; j++) a = fmaf(S1sh[l][j], qrow[j], a);
            float bb2 = 0.f;
#pragma unroll
            for (int m = 0; m < LC; m++) bb2 = fmaf(Btsh[l][m], Vsh[m][d], bb2);
            av[l] = a; bv[l] = bb2; vv[l] = Vsh[l][d];
        }
#pragma unroll
        for (int lg = 0; lg < 5; lg++) {
            float4 o1, o2, o3, o4;
            o1.x = vv[lg*4+0]; o1.y = vv[lg*4+1]; o1.z = vv[lg*4+2]; o1.w = vv[lg*4+3];
            o2.x = av[lg*4+0]; o2.y = av[lg*4+1]; o2.z = av[lg*4+2]; o2.w = av[lg*4+3];
            o3.x = o1.x*o2.x;  o3.y = o1.y*o2.y;  o3.z = o1.z*o2.z;  o3.w = o1.w*o2.w;
            o4.x = o1.x*bv[lg*4+0]; o4.y = o1.y*bv[lg*4+1];
            o4.z = o1.z*bv[lg*4+2]; o4.w = o1.w*bv[lg*4+3];
            *reinterpret_cast<float4*>(&outb[(size_t)d * LC + lg * 4]) = o1;
            *reinterpret_cast<float4*>(&outb[(size_t)(CTXM + d) * LC + lg * 4]) = o2;
            *reinterpret_cast<float4*>(&outb[(size_t)(2 * CTXM + d) * LC + lg * 4]) = o3;
            *reinterpret_cast<float4*>(&outb[(size_t)(3 * CTXM + d) * LC + lg * 4]) = o4;
        }
    }
}

extern "C" void kernel_launch(void* const* d_in, const int* in_sizes, int n_in,
                              void* d_out, int out_size, void* d_ws, size_t ws_size,
                              hipStream_t stream) {
    const float* Vid   = (const float*)d_in[0];
    const float* Ques  = (const float*)d_in[1];
    const float* Vmask = (const float*)d_in[2];
    const float* Qmask = (const float*)d_in[3];
    const float* tv    = (const float*)d_in[4];
    const float* tg    = (const float*)d_in[5];
    const float* tb    = (const float*)d_in[6];
    const float* w4V   = (const float*)d_in[7];
    const float* w4Q   = (const float*)d_in[8];
    const float* w4mlu = (const float*)d_in[9];
    const float* bias  = (const float*)d_in[10];
    float* out = (float*)d_out;

    float* scale = (float*)d_ws;          // 512 floats
    float* V     = scale + 512;           // 40960*512 floats (84 MB)

    scale_kernel<<<512, 256, 0, stream>>>(tv, tg, scale);
    gemm_kernel<<<dim3(CTXM / BN, (B_ * LC) / BM), 256, 0, stream>>>(Vid, tv, scale, tb, V);
    attn_kernel<<<B_, 256, 0, stream>>>(Ques, Vmask, Qmask, w4V, w4Q, w4mlu, bias, V, out);
}

// Round 2
// 1666.661 us; speedup vs baseline: 2.2711x; 2.2711x over previous
//
#include <hip/hip_runtime.h>
#include <math.h>

#define B_    2048
#define LC    20
#define LQ    50
#define CTX   2048
#define CTXM  512
#define NEGV  -1e30f

// ---------------- Kernel 1: per-row scale = g[m] / ||trans_v[m,:]|| ----------------
__global__ __launch_bounds__(256)
void scale_kernel(const float* __restrict__ trans_v,
                  const float* __restrict__ trans_g,
                  float* __restrict__ scale) {
    int m = blockIdx.x;
    int t = threadIdx.x;
    const float* row = trans_v + (size_t)m * CTX;
    float ss = 0.f;
    for (int i = t; i < CTX; i += 256) { float v = row[i]; ss += v * v; }
    __shared__ float red[256];
    red[t] = ss;
    __syncthreads();
    for (int s = 128; s > 0; s >>= 1) {
        if (t < s) red[t] += red[t + s];
        __syncthreads();
    }
    if (t == 0) scale[m] = trans_g[m] / sqrtf(red[0]);
}

// ---------------- Kernel 2: V = Vid(40960x2048) @ (scale*trans_v)^T + trans_b ----------------
#define BM 128
#define BN 128
#define BK 32

__global__ __launch_bounds__(256)
void gemm_kernel(const float* __restrict__ A,        // (40960, 2048)
                 const float* __restrict__ Wt,       // (512, 2048) = trans_v
                 const float* __restrict__ scale,    // (512)
                 const float* __restrict__ trans_b,  // (512)
                 float* __restrict__ V)              // (40960, 512)
{
    __shared__ float As[BK][BM + 4];
    __shared__ float Bs[BK][BN + 4];
    __shared__ float sc[BN];

    int t  = threadIdx.x;
    int n0 = blockIdx.x * BN;
    int m0 = blockIdx.y * BM;
    int tx = t & 15, ty = t >> 4;

    if (t < BN) sc[t] = scale[n0 + t];

    float acc[8][8];
#pragma unroll
    for (int i = 0; i < 8; i++)
#pragma unroll
        for (int j = 0; j < 8; j++) acc[i][j] = 0.f;

    __syncthreads();

    for (int k0 = 0; k0 < CTX; k0 += BK) {
#pragma unroll
        for (int i = 0; i < 4; ++i) {
            int f4 = t + i * 256;
            int r  = f4 >> 3;
            int kc = (f4 & 7) << 2;
            const float4 v = *reinterpret_cast<const float4*>(
                &A[(size_t)(m0 + r) * CTX + k0 + kc]);
            As[kc + 0][r] = v.x; As[kc + 1][r] = v.y;
            As[kc + 2][r] = v.z; As[kc + 3][r] = v.w;
        }
#pragma unroll
        for (int i = 0; i < 4; ++i) {
            int f4 = t + i * 256;
            int r  = f4 >> 3;
            int kc = (f4 & 7) << 2;
            float s = sc[r];
            const float4 v = *reinterpret_cast<const float4*>(
                &Wt[(size_t)(n0 + r) * CTX + k0 + kc]);
            Bs[kc + 0][r] = v.x * s; Bs[kc + 1][r] = v.y * s;
            Bs[kc + 2][r] = v.z * s; Bs[kc + 3][r] = v.w * s;
        }
        __syncthreads();
#pragma unroll
        for (int kk = 0; kk < BK; ++kk) {
            float a[8], b[8];
            *(float4*)&a[0] = *(const float4*)&As[kk][ty * 8];
            *(float4*)&a[4] = *(const float4*)&As[kk][ty * 8 + 4];
            *(float4*)&b[0] = *(const float4*)&Bs[kk][tx * 8];
            *(float4*)&b[4] = *(const float4*)&Bs[kk][tx * 8 + 4];
#pragma unroll
            for (int i = 0; i < 8; i++)
#pragma unroll
                for (int j = 0; j < 8; j++)
                    acc[i][j] = fmaf(a[i], b[j], acc[i][j]);
        }
        __syncthreads();
    }

#pragma unroll
    for (int i = 0; i < 8; i++) {
        size_t m = (size_t)(m0 + ty * 8 + i);
#pragma unroll
        for (int j0 = 0; j0 < 8; j0 += 4) {
            int n = n0 + tx * 8 + j0;
            float4 o;
            o.x = acc[i][j0 + 0] + trans_b[n + 0];
            o.y = acc[i][j0 + 1] + trans_b[n + 1];
            o.z = acc[i][j0 + 2] + trans_b[n + 2];
            o.w = acc[i][j0 + 3] + trans_b[n + 3];
            *reinterpret_cast<float4*>(&V[m * CTXM + n]) = o;
        }
    }
}

// ---------------- Kernel 3: per-batch attention + epilogue (d-chunked) ----------------
#define DCH 64   // d-chunk size (512/64 = 8 chunks)

__global__ __launch_bounds__(256)
void attn_kernel(const float* __restrict__ Ques,    // (B, 512, 50)
                 const float* __restrict__ V_mask,  // (B, 20)
                 const float* __restrict__ Q_mask,  // (B, 50)
                 const float* __restrict__ w4V,     // (512)
                 const float* __restrict__ w4Q,     // (512)
                 const float* __restrict__ w4mlu,   // (512)
                 const float* __restrict__ bias,    // (1)
                 const float* __restrict__ V,       // (B*20, 512)
                 float* __restrict__ out)           // (B, 2048, 20)
{
    __shared__ float Vsh[LC][CTXM];        // 40 KB
    __shared__ float wmsh[CTXM];           // 2 KB
    __shared__ float Qch[DCH * LQ];        // 12.8 KB, flat [dloc*50+q]
    __shared__ float Ssh[LC][LQ];          // 4 KB
    __shared__ float S1sh[LC][LQ];         // 4 KB
    __shared__ float S2sh[LC][LQ];         // 4 KB
    __shared__ float Btsh[LC][LC];         // 1.6 KB
    __shared__ float s0sh[LC];
    __shared__ float s1qsh[LQ];
    __shared__ float s0p[LC][8];
    __shared__ float qmsh[LQ];
    __shared__ float vmsh[LC];

    int b = blockIdx.x;
    int t = threadIdx.x;
    const float* Vb = V + (size_t)b * (LC * CTXM);
    const float* Qb = Ques + (size_t)b * (CTXM * LQ);

    // stage V (20x512 = 2560 float4, contiguous)
    {
        const float4* src = reinterpret_cast<const float4*>(Vb);
        float4* dst = reinterpret_cast<float4*>(&Vsh[0][0]);
#pragma unroll
        for (int i = 0; i < 10; i++) dst[t + i * 256] = src[t + i * 256];
    }
    for (int i = t; i < CTXM; i += 256) wmsh[i] = w4mlu[i];
    if (t < LQ) qmsh[t] = Q_mask[(size_t)b * LQ + t];
    if (t < LC) vmsh[t] = V_mask[(size_t)b * LC + t];
    __syncthreads();

    // s0[l] = sum_d V[l,d]*w4V[d]
    if (t < LC * 8) {
        int l = t >> 3, lane = t & 7;
        float acc = 0.f;
        for (int d = lane; d < CTXM; d += 8) acc += Vsh[l][d] * w4V[d];
        s0p[l][lane] = acc;
    }
    __syncthreads();
    if (t < LC) {
        float s = 0.f;
#pragma unroll
        for (int i = 0; i < 8; i++) s += s0p[t][i];
        s0sh[t] = s;
    }

    // ---- Pass 1 over Q chunks: s2 (per-thread 4 l x 1 q) and s1 ----
    float acc2[4] = {0.f, 0.f, 0.f, 0.f};
    int q  = t % LQ;          // valid for t < 250
    int l0 = (t / LQ) * 4;
    float s1acc = 0.f;
    for (int c = 0; c < CTXM / DCH; ++c) {
        int d0 = c * DCH;
        __syncthreads();
        // stage Qch: contiguous DCH*LQ = 3200 floats = 800 float4
        {
            const float4* src = reinterpret_cast<const float4*>(Qb + (size_t)d0 * LQ);
            float4* dst = reinterpret_cast<float4*>(Qch);
            for (int j = t; j < (DCH * LQ) / 4; j += 256) dst[j] = src[j];
        }
        __syncthreads();
        if (t < 250) {
#pragma unroll
            for (int dd = 0; dd < DCH; ++dd) {
                float wq = wmsh[d0 + dd] * Qch[dd * LQ + q];
                acc2[0] = fmaf(Vsh[l0 + 0][d0 + dd], wq, acc2[0]);
                acc2[1] = fmaf(Vsh[l0 + 1][d0 + dd], wq, acc2[1]);
                acc2[2] = fmaf(Vsh[l0 + 2][d0 + dd], wq, acc2[2]);
                acc2[3] = fmaf(Vsh[l0 + 3][d0 + dd], wq, acc2[3]);
            }
        }
        if (t < LQ) {
#pragma unroll
            for (int dd = 0; dd < DCH; ++dd)
                s1acc = fmaf(Qch[dd * LQ + t], w4Q[d0 + dd], s1acc);
        }
    }
    if (t < LQ) s1qsh[t] = s1acc;
    __syncthreads();

    // S = s0 + s1 + s2 + bias
    if (t < 250) {
        float bb = bias[0];
#pragma unroll
        for (int i = 0; i < 4; i++)
            Ssh[l0 + i][q] = acc2[i] + s0sh[l0 + i] + s1qsh[q] + bb;
    }
    __syncthreads();

    // S1: softmax over q (rows); S2: softmax over l (cols)
    if (t < LC) {
        int l = t;
        float mx = -INFINITY;
        for (int j = 0; j < LQ; j++) {
            float qm = qmsh[j];
            float x = Ssh[l][j] * qm + (1.f - qm) * NEGV;
            mx = fmaxf(mx, x);
        }
        float sum = 0.f;
        for (int j = 0; j < LQ; j++) {
            float qm = qmsh[j];
            float x = Ssh[l][j] * qm + (1.f - qm) * NEGV;
            float e = expf(x - mx);
            S1sh[l][j] = e;
            sum += e;
        }
        float inv = 1.f / sum;
        for (int j = 0; j < LQ; j++) S1sh[l][j] *= inv;
    } else if (t >= 64 && t < 64 + LQ) {
        int j = t - 64;
        float mx = -INFINITY;
        for (int l = 0; l < LC; l++) {
            float vm = vmsh[l];
            float x = Ssh[l][j] * vm + (1.f - vm) * NEGV;
            mx = fmaxf(mx, x);
        }
        float sum = 0.f;
        for (int l = 0; l < LC; l++) {
            float vm = vmsh[l];
            float x = Ssh[l][j] * vm + (1.f - vm) * NEGV;
            float e = expf(x - mx);
            S2sh[l][j] = e;
            sum += e;
        }
        float inv = 1.f / sum;
        for (int l = 0; l < LC; l++) S2sh[l][j] *= inv;
    }
    __syncthreads();

    // Bt[l][m] = sum_q S1[l,q]*S2[m,q]
    for (int p = t; p < LC * LC; p += 256) {
        int l = p / LC, m = p % LC;
        float s = 0.f;
        for (int j = 0; j < LQ; j++) s += S1sh[l][j] * S2sh[m][j];
        Btsh[l][m] = s;
    }

    // ---- Pass 2 over Q chunks: A, Bv, write all 4 sections coalesced ----
    float* outb = out + (size_t)b * (4 * CTXM * LC);
    for (int c = 0; c < CTXM / DCH; ++c) {
        int d0 = c * DCH;
        __syncthreads();   // protect Qch (and, at c=0, Btsh/S1sh writers)
        {
            const float4* src = reinterpret_cast<const float4*>(Qb + (size_t)d0 * LQ);
            float4* dst = reinterpret_cast<float4*>(Qch);
            for (int j = t; j < (DCH * LQ) / 4; j += 256) dst[j] = src[j];
        }
        __syncthreads();
        // 1280 outputs per section this chunk; p = dloc*20 + l (matches flat layout)
#pragma unroll
        for (int i = 0; i < 5; ++i) {
            int p = t + i * 256;          // 0..1279
            int dloc = p / LC;
            int l = p % LC;
            int d = d0 + dloc;
            float a = 0.f;
            const float* s1r = &S1sh[l][0];
            const float* qr  = &Qch[dloc * LQ];
#pragma unroll
            for (int j = 0; j < LQ; j++) a = fmaf(s1r[j], qr[j], a);
            float bv = 0.f;
            const float* btr = &Btsh[l][0];
#pragma unroll
            for (int m = 0; m < LC; m++) bv = fmaf(btr[m], Vsh[m][d], bv);
            float v = Vsh[l][d];
            int base = d0 * LC + p;       // contiguous across threads
            outb[base]                    = v;
            outb[base + 1 * CTXM * LC]    = a;
            outb[base + 2 * CTXM * LC]    = v * a;
            outb[base + 3 * CTXM * LC]    = v * bv;
        }
    }
}

extern "C" void kernel_launch(void* const* d_in, const int* in_sizes, int n_in,
                              void* d_out, int out_size, void* d_ws, size_t ws_size,
                              hipStream_t stream) {
    const float* Vid   = (const float*)d_in[0];
    const float* Ques  = (const float*)d_in[1];
    const float* Vmask = (const float*)d_in[2];
    const float* Qmask = (const float*)d_in[3];
    const float* tv    = (const float*)d_in[4];
    const float* tg    = (const float*)d_in[5];
    const float* tb    = (const float*)d_in[6];
    const float* w4V   = (const float*)d_in[7];
    const float* w4Q   = (const float*)d_in[8];
    const float* w4mlu = (const float*)d_in[9];
    const float* bias  = (const float*)d_in[10];
    float* out = (float*)d_out;

    float* scale = (float*)d_ws;          // 512 floats
    float* V     = scale + 512;           // 40960*512 floats (84 MB)

    scale_kernel<<<512, 256, 0, stream>>>(tv, tg, scale);
    gemm_kernel<<<dim3(CTXM / BN, (B_ * LC) / BM), 256, 0, stream>>>(Vid, tv, scale, tb, V);
    attn_kernel<<<B_, 256, 0, stream>>>(Ques, Vmask, Qmask, w4V, w4Q, w4mlu, bias, V, out);
}

// Round 3
// 1032.326 us; speedup vs baseline: 3.6667x; 1.6145x over previous
//
#include <hip/hip_runtime.h>
#include <math.h>

#define B_    2048
#define LC    20
#define LQ    50
#define CTX   2048
#define CTXM  512
#define NEGV  -1e30f

typedef short bf16x8 __attribute__((ext_vector_type(8)));
typedef float f32x4  __attribute__((ext_vector_type(4)));
typedef unsigned int uint;

// ---------------- Kernel 1: per-row scale = g[m] / ||trans_v[m,:]|| ----------------
__global__ __launch_bounds__(256)
void scale_kernel(const float* __restrict__ trans_v,
                  const float* __restrict__ trans_g,
                  float* __restrict__ scale) {
    int m = blockIdx.x;
    int t = threadIdx.x;
    const float* row = trans_v + (size_t)m * CTX;
    float ss = 0.f;
    for (int i = t; i < CTX; i += 256) { float v = row[i]; ss += v * v; }
    __shared__ float red[256];
    red[t] = ss;
    __syncthreads();
    for (int s = 128; s > 0; s >>= 1) {
        if (t < s) red[t] += red[t + s];
        __syncthreads();
    }
    if (t == 0) scale[m] = trans_g[m] / sqrtf(red[0]);
}

// ---------------- Kernel 2: bf16-split MFMA GEMM ----------------
// V(40960x512) = Vid(40960x2048) @ (scale*trans_v)^T + trans_b
// x = x_hi + x_lo (hi = top-16 truncate, lo = bf16 of remainder)
// A@B ~= Ah Bh + Al Bh + Ah Bl   (error ~2^-17 relative)
#define GKB 32   // fp32 k per tile

__device__ __forceinline__ void split4(float a0, float a1, float a2, float a3,
                                       uint2& hi, uint2& lo) {
    uint x0 = __float_as_uint(a0), x1 = __float_as_uint(a1),
         x2 = __float_as_uint(a2), x3 = __float_as_uint(a3);
    uint l0 = __float_as_uint(a0 - __uint_as_float(x0 & 0xffff0000u));
    uint l1 = __float_as_uint(a1 - __uint_as_float(x1 & 0xffff0000u));
    uint l2 = __float_as_uint(a2 - __uint_as_float(x2 & 0xffff0000u));
    uint l3 = __float_as_uint(a3 - __uint_as_float(x3 & 0xffff0000u));
    // pack top16(b)<<16 | top16(a):  D = [S0.b3,S0.b2,S1.b3,S1.b2]
    hi.x = __builtin_amdgcn_perm(x1, x0, 0x07060302u);
    hi.y = __builtin_amdgcn_perm(x3, x2, 0x07060302u);
    lo.x = __builtin_amdgcn_perm(l1, l0, 0x07060302u);
    lo.y = __builtin_amdgcn_perm(l3, l2, 0x07060302u);
}

__global__ __launch_bounds__(256)
void gemm_kernel(const float* __restrict__ A,        // (40960, 2048)
                 const float* __restrict__ Wt,       // (512, 2048)
                 const float* __restrict__ scale,    // (512)
                 const float* __restrict__ trans_b,  // (512)
                 float* __restrict__ V)              // (40960, 512)
{
    // per row (128B): bytes [0,64) = hi (32 bf16), [64,128) = lo
    // swizzle: byte_in_row ^ ((row&7)<<4)  on both write and read
    __shared__ char Ash[128 * 128] __attribute__((aligned(16)));
    __shared__ char Bsh[128 * 128] __attribute__((aligned(16)));
    __shared__ float sc[128];

    int t = threadIdx.x;
    // bijective XCD chunk swizzle: 1280 blocks -> 8 chunks of 160
    int orig = blockIdx.x;
    int wg = (orig & 7) * 160 + (orig >> 3);
    int n0 = (wg & 3) * 128;
    int m0 = (wg >> 2) * 128;

    if (t < 128) sc[t] = scale[n0 + t];

    int wid  = t >> 6;
    int lane = t & 63;
    int wm = (wid >> 1) << 6;   // 0/64
    int wn = (wid & 1) << 6;    // 0/64

    f32x4 acc[4][4];
#pragma unroll
    for (int i = 0; i < 4; i++)
#pragma unroll
        for (int j = 0; j < 4; j++) acc[i][j] = (f32x4){0.f, 0.f, 0.f, 0.f};

    int f4r[4], f4c[4];
    float4 ra[4], rb[4];
#pragma unroll
    for (int i = 0; i < 4; i++) {
        int f4 = t + i * 256;
        f4r[i] = f4 >> 3;          // tile row 0..127
        f4c[i] = (f4 & 7) << 2;    // fp32 col 0..28
        ra[i] = *(const float4*)&A [(size_t)(m0 + f4r[i]) * CTX + f4c[i]];
        rb[i] = *(const float4*)&Wt[(size_t)(n0 + f4r[i]) * CTX + f4c[i]];
    }
    __syncthreads();   // sc ready

    for (int it = 0; it < CTX / GKB; ++it) {
        // ---- convert + LDS write ----
#pragma unroll
        for (int i = 0; i < 4; i++) {
            int r  = f4r[i];
            int c8 = (f4c[i] >> 2) << 3;     // byte offset in hi half
            int sw = (r & 7) << 4;
            uint2 hi, lo;
            split4(ra[i].x, ra[i].y, ra[i].z, ra[i].w, hi, lo);
            *(uint2*)&Ash[r * 128 + (c8 ^ sw)]        = hi;
            *(uint2*)&Ash[r * 128 + ((64 + c8) ^ sw)] = lo;
            float s = sc[r];
            split4(rb[i].x * s, rb[i].y * s, rb[i].z * s, rb[i].w * s, hi, lo);
            *(uint2*)&Bsh[r * 128 + (c8 ^ sw)]        = hi;
            *(uint2*)&Bsh[r * 128 + ((64 + c8) ^ sw)] = lo;
        }
        __syncthreads();

        // ---- prefetch next tile (overlaps MFMA phase) ----
        if (it + 1 < CTX / GKB) {
            int k0 = (it + 1) * GKB;
#pragma unroll
            for (int i = 0; i < 4; i++) {
                ra[i] = *(const float4*)&A [(size_t)(m0 + f4r[i]) * CTX + k0 + f4c[i]];
                rb[i] = *(const float4*)&Wt[(size_t)(n0 + f4r[i]) * CTX + k0 + f4c[i]];
            }
        }

        // ---- fragments + 48 MFMAs ----
        int q16 = (lane >> 4) << 4;
        bf16x8 ah[4], al[4], bx[4];
#pragma unroll
        for (int mt = 0; mt < 4; mt++) {
            int r  = wm + mt * 16 + (lane & 15);
            int sw = (r & 7) << 4;
            ah[mt] = *(const bf16x8*)&Ash[r * 128 + (q16 ^ sw)];
            al[mt] = *(const bf16x8*)&Ash[r * 128 + ((64 + q16) ^ sw)];
        }
#pragma unroll
        for (int nt = 0; nt < 4; nt++) {
            int r  = wn + nt * 16 + (lane & 15);
            int sw = (r & 7) << 4;
            bx[nt] = *(const bf16x8*)&Bsh[r * 128 + (q16 ^ sw)];   // Bh
        }
#pragma unroll
        for (int mt = 0; mt < 4; mt++)
#pragma unroll
            for (int nt = 0; nt < 4; nt++)
                acc[mt][nt] = __builtin_amdgcn_mfma_f32_16x16x32_bf16(ah[mt], bx[nt], acc[mt][nt], 0, 0, 0);
#pragma unroll
        for (int mt = 0; mt < 4; mt++)
#pragma unroll
            for (int nt = 0; nt < 4; nt++)
                acc[mt][nt] = __builtin_amdgcn_mfma_f32_16x16x32_bf16(al[mt], bx[nt], acc[mt][nt], 0, 0, 0);
#pragma unroll
        for (int nt = 0; nt < 4; nt++) {
            int r  = wn + nt * 16 + (lane & 15);
            int sw = (r & 7) << 4;
            bx[nt] = *(const bf16x8*)&Bsh[r * 128 + ((64 + q16) ^ sw)];  // Bl
        }
#pragma unroll
        for (int mt = 0; mt < 4; mt++)
#pragma unroll
            for (int nt = 0; nt < 4; nt++)
                acc[mt][nt] = __builtin_amdgcn_mfma_f32_16x16x32_bf16(ah[mt], bx[nt], acc[mt][nt], 0, 0, 0);
        __syncthreads();
    }

    // ---- epilogue: +trans_b, store ----
    int colbase = n0 + wn + (lane & 15);
    int rq4 = (lane >> 4) << 2;
#pragma unroll
    for (int nt = 0; nt < 4; nt++) {
        int col = colbase + nt * 16;
        float tb = trans_b[col];
#pragma unroll
        for (int mt = 0; mt < 4; mt++) {
            int m = m0 + wm + mt * 16 + rq4;
#pragma unroll
            for (int rg = 0; rg < 4; rg++)
                V[(size_t)(m + rg) * CTXM + col] = acc[mt][nt][rg] + tb;
        }
    }
}

// ---------------- Kernel 3: per-batch attention + epilogue (d-chunked) ----------------
#define DCH 64   // d-chunk size (512/64 = 8 chunks)

__global__ __launch_bounds__(256)
void attn_kernel(const float* __restrict__ Ques,    // (B, 512, 50)
                 const float* __restrict__ V_mask,  // (B, 20)
                 const float* __restrict__ Q_mask,  // (B, 50)
                 const float* __restrict__ w4V,     // (512)
                 const float* __restrict__ w4Q,     // (512)
                 const float* __restrict__ w4mlu,   // (512)
                 const float* __restrict__ bias,    // (1)
                 const float* __restrict__ V,       // (B*20, 512)
                 float* __restrict__ out)           // (B, 2048, 20)
{
    __shared__ float Vsh[LC][CTXM];        // 40 KB
    __shared__ float wmsh[CTXM];
    __shared__ float Qch[DCH * LQ];        // 12.8 KB
    __shared__ float Ssh[LC][LQ];
    __shared__ float S1sh[LC][LQ];
    __shared__ float S2sh[LC][LQ];
    __shared__ float Btsh[LC][LC];
    __shared__ float s0sh[LC];
    __shared__ float s1qsh[LQ];
    __shared__ float s0p[LC][8];
    __shared__ float qmsh[LQ];
    __shared__ float vmsh[LC];

    int b = blockIdx.x;
    int t = threadIdx.x;
    const float* Vb = V + (size_t)b * (LC * CTXM);
    const float* Qb = Ques + (size_t)b * (CTXM * LQ);

    {
        const float4* src = reinterpret_cast<const float4*>(Vb);
        float4* dst = reinterpret_cast<float4*>(&Vsh[0][0]);
#pragma unroll
        for (int i = 0; i < 10; i++) dst[t + i * 256] = src[t + i * 256];
    }
    for (int i = t; i < CTXM; i += 256) wmsh[i] = w4mlu[i];
    if (t < LQ) qmsh[t] = Q_mask[(size_t)b * LQ + t];
    if (t < LC) vmsh[t] = V_mask[(size_t)b * LC + t];
    __syncthreads();

    if (t < LC * 8) {
        int l = t >> 3, lane = t & 7;
        float acc = 0.f;
        for (int d = lane; d < CTXM; d += 8) acc += Vsh[l][d] * w4V[d];
        s0p[l][lane] = acc;
    }
    __syncthreads();
    if (t < LC) {
        float s = 0.f;
#pragma unroll
        for (int i = 0; i < 8; i++) s += s0p[t][i];
        s0sh[t] = s;
    }

    float acc2[4] = {0.f, 0.f, 0.f, 0.f};
    int q  = t % LQ;
    int l0 = (t / LQ) * 4;
    float s1acc = 0.f;
    for (int c = 0; c < CTXM / DCH; ++c) {
        int d0 = c * DCH;
        __syncthreads();
        {
            const float4* src = reinterpret_cast<const float4*>(Qb + (size_t)d0 * LQ);
            float4* dst = reinterpret_cast<float4*>(Qch);
            for (int j = t; j < (DCH * LQ) / 4; j += 256) dst[j] = src[j];
        }
        __syncthreads();
        if (t < 250) {
#pragma unroll
            for (int dd = 0; dd < DCH; ++dd) {
                float wq = wmsh[d0 + dd] * Qch[dd * LQ + q];
                acc2[0] = fmaf(Vsh[l0 + 0][d0 + dd], wq, acc2[0]);
                acc2[1] = fmaf(Vsh[l0 + 1][d0 + dd], wq, acc2[1]);
                acc2[2] = fmaf(Vsh[l0 + 2][d0 + dd], wq, acc2[2]);
                acc2[3] = fmaf(Vsh[l0 + 3][d0 + dd], wq, acc2[3]);
            }
        }
        if (t < LQ) {
#pragma unroll
            for (int dd = 0; dd < DCH; ++dd)
                s1acc = fmaf(Qch[dd * LQ + t], w4Q[d0 + dd], s1acc);
        }
    }
    if (t < LQ) s1qsh[t] = s1acc;
    __syncthreads();

    if (t < 250) {
        float bb = bias[0];
#pragma unroll
        for (int i = 0; i < 4; i++)
            Ssh[l0 + i][q] = acc2[i] + s0sh[l0 + i] + s1qsh[q] + bb;
    }
    __syncthreads();

    if (t < LC) {
        int l = t;
        float mx = -INFINITY;
        for (int j = 0; j < LQ; j++) {
            float qm = qmsh[j];
            float x = Ssh[l][j] * qm + (1.f - qm) * NEGV;
            mx = fmaxf(mx, x);
        }
        float sum = 0.f;
        for (int j = 0; j < LQ; j++) {
            float qm = qmsh[j];
            float x = Ssh[l][j] * qm + (1.f - qm) * NEGV;
            float e = expf(x - mx);
            S1sh[l][j] = e;
            sum += e;
        }
        float inv = 1.f / sum;
        for (int j = 0; j < LQ; j++) S1sh[l][j] *= inv;
    } else if (t >= 64 && t < 64 + LQ) {
        int j = t - 64;
        float mx = -INFINITY;
        for (int l = 0; l < LC; l++) {
            float vm = vmsh[l];
            float x = Ssh[l][j] * vm + (1.f - vm) * NEGV;
            mx = fmaxf(mx, x);
        }
        float sum = 0.f;
        for (int l = 0; l < LC; l++) {
            float vm = vmsh[l];
            float x = Ssh[l][j] * vm + (1.f - vm) * NEGV;
            float e = expf(x - mx);
            S2sh[l][j] = e;
            sum += e;
        }
        float inv = 1.f / sum;
        for (int l = 0; l < LC; l++) S2sh[l][j] *= inv;
    }
    __syncthreads();

    for (int p = t; p < LC * LC; p += 256) {
        int l = p / LC, m = p % LC;
        float s = 0.f;
        for (int j = 0; j < LQ; j++) s += S1sh[l][j] * S2sh[m][j];
        Btsh[l][m] = s;
    }

    float* outb = out + (size_t)b * (4 * CTXM * LC);
    for (int c = 0; c < CTXM / DCH; ++c) {
        int d0 = c * DCH;
        __syncthreads();
        {
            const float4* src = reinterpret_cast<const float4*>(Qb + (size_t)d0 * LQ);
            float4* dst = reinterpret_cast<float4*>(Qch);
            for (int j = t; j < (DCH * LQ) / 4; j += 256) dst[j] = src[j];
        }
        __syncthreads();
#pragma unroll
        for (int i = 0; i < 5; ++i) {
            int p = t + i * 256;
            int dloc = p / LC;
            int l = p % LC;
            int d = d0 + dloc;
            float a = 0.f;
            const float* s1r = &S1sh[l][0];
            const float* qr  = &Qch[dloc * LQ];
#pragma unroll
            for (int j = 0; j < LQ; j++) a = fmaf(s1r[j], qr[j], a);
            float bv = 0.f;
            const float* btr = &Btsh[l][0];
#pragma unroll
            for (int m = 0; m < LC; m++) bv = fmaf(btr[m], Vsh[m][d], bv);
            float v = Vsh[l][d];
            int base = d0 * LC + p;
            outb[base]                    = v;
            outb[base + 1 * CTXM * LC]    = a;
            outb[base + 2 * CTXM * LC]    = v * a;
            outb[base + 3 * CTXM * LC]    = v * bv;
        }
    }
}

extern "C" void kernel_launch(void* const* d_in, const int* in_sizes, int n_in,
                              void* d_out, int out_size, void* d_ws, size_t ws_size,
                              hipStream_t stream) {
    const float* Vid   = (const float*)d_in[0];
    const float* Ques  = (const float*)d_in[1];
    const float* Vmask = (const float*)d_in[2];
    const float* Qmask = (const float*)d_in[3];
    const float* tv    = (const float*)d_in[4];
    const float* tg    = (const float*)d_in[5];
    const float* tb    = (const float*)d_in[6];
    const float* w4V   = (const float*)d_in[7];
    const float* w4Q   = (const float*)d_in[8];
    const float* w4mlu = (const float*)d_in[9];
    const float* bias  = (const float*)d_in[10];
    float* out = (float*)d_out;

    float* scale = (float*)d_ws;          // 512 floats
    float* V     = scale + 512;           // 40960*512 floats (84 MB)

    scale_kernel<<<512, 256, 0, stream>>>(tv, tg, scale);
    gemm_kernel<<<1280, 256, 0, stream>>>(Vid, tv, scale, tb, V);
    attn_kernel<<<B_, 256, 0, stream>>>(Ques, Vmask, Qmask, w4V, w4Q, w4mlu, bias, V, out);
}

// Round 4
// 618.808 us; speedup vs baseline: 6.1169x; 1.6682x over previous
//
#include <hip/hip_runtime.h>
#include <math.h>

#define B_    2048
#define LC    20
#define LQ    50
#define CTX   2048
#define CTXM  512
#define NEGV  -1e30f

typedef short bf16x8 __attribute__((ext_vector_type(8)));
typedef float f32x4  __attribute__((ext_vector_type(4)));
typedef unsigned int uint;

// ---------------- helpers: fp32 -> bf16 hi/lo split ----------------
__device__ __forceinline__ void split4(float a0, float a1, float a2, float a3,
                                       uint2& hi, uint2& lo) {
    uint x0 = __float_as_uint(a0), x1 = __float_as_uint(a1),
         x2 = __float_as_uint(a2), x3 = __float_as_uint(a3);
    uint l0 = __float_as_uint(a0 - __uint_as_float(x0 & 0xffff0000u));
    uint l1 = __float_as_uint(a1 - __uint_as_float(x1 & 0xffff0000u));
    uint l2 = __float_as_uint(a2 - __uint_as_float(x2 & 0xffff0000u));
    uint l3 = __float_as_uint(a3 - __uint_as_float(x3 & 0xffff0000u));
    hi.x = __builtin_amdgcn_perm(x1, x0, 0x07060302u);
    hi.y = __builtin_amdgcn_perm(x3, x2, 0x07060302u);
    lo.x = __builtin_amdgcn_perm(l1, l0, 0x07060302u);
    lo.y = __builtin_amdgcn_perm(l3, l2, 0x07060302u);
}

__device__ __forceinline__ void split8(const float* x, bf16x8& h, bf16x8& l) {
    uint2 h0, l0, h1, l1;
    split4(x[0], x[1], x[2], x[3], h0, l0);
    split4(x[4], x[5], x[6], x[7], h1, l1);
    union { uint u[4]; bf16x8 v; } H, L;
    H.u[0] = h0.x; H.u[1] = h0.y; H.u[2] = h1.x; H.u[3] = h1.y;
    L.u[0] = l0.x; L.u[1] = l0.y; L.u[2] = l1.x; L.u[3] = l1.y;
    h = H.v; l = L.v;
}

// ---------------- Kernel 1: per-row scale = g[m] / ||trans_v[m,:]|| ----------------
__global__ __launch_bounds__(256)
void scale_kernel(const float* __restrict__ trans_v,
                  const float* __restrict__ trans_g,
                  float* __restrict__ scale) {
    int m = blockIdx.x;
    int t = threadIdx.x;
    const float* row = trans_v + (size_t)m * CTX;
    float ss = 0.f;
    for (int i = t; i < CTX; i += 256) { float v = row[i]; ss += v * v; }
    __shared__ float red[256];
    red[t] = ss;
    __syncthreads();
    for (int s = 128; s > 0; s >>= 1) {
        if (t < s) red[t] += red[t + s];
        __syncthreads();
    }
    if (t == 0) scale[m] = trans_g[m] / sqrtf(red[0]);
}

// ---------------- Kernel 2: bf16-split MFMA GEMM (unchanged from R2) ----------------
#define GKB 32

__global__ __launch_bounds__(256)
void gemm_kernel(const float* __restrict__ A,
                 const float* __restrict__ Wt,
                 const float* __restrict__ scale,
                 const float* __restrict__ trans_b,
                 float* __restrict__ V)
{
    __shared__ char Ash[128 * 128] __attribute__((aligned(16)));
    __shared__ char Bsh[128 * 128] __attribute__((aligned(16)));
    __shared__ float sc[128];

    int t = threadIdx.x;
    int orig = blockIdx.x;
    int wg = (orig & 7) * 160 + (orig >> 3);
    int n0 = (wg & 3) * 128;
    int m0 = (wg >> 2) * 128;

    if (t < 128) sc[t] = scale[n0 + t];

    int wid  = t >> 6;
    int lane = t & 63;
    int wm = (wid >> 1) << 6;
    int wn = (wid & 1) << 6;

    f32x4 acc[4][4];
#pragma unroll
    for (int i = 0; i < 4; i++)
#pragma unroll
        for (int j = 0; j < 4; j++) acc[i][j] = (f32x4){0.f, 0.f, 0.f, 0.f};

    int f4r[4], f4c[4];
    float4 ra[4], rb[4];
#pragma unroll
    for (int i = 0; i < 4; i++) {
        int f4 = t + i * 256;
        f4r[i] = f4 >> 3;
        f4c[i] = (f4 & 7) << 2;
        ra[i] = *(const float4*)&A [(size_t)(m0 + f4r[i]) * CTX + f4c[i]];
        rb[i] = *(const float4*)&Wt[(size_t)(n0 + f4r[i]) * CTX + f4c[i]];
    }
    __syncthreads();

    for (int it = 0; it < CTX / GKB; ++it) {
#pragma unroll
        for (int i = 0; i < 4; i++) {
            int r  = f4r[i];
            int c8 = (f4c[i] >> 2) << 3;
            int sw = (r & 7) << 4;
            uint2 hi, lo;
            split4(ra[i].x, ra[i].y, ra[i].z, ra[i].w, hi, lo);
            *(uint2*)&Ash[r * 128 + (c8 ^ sw)]        = hi;
            *(uint2*)&Ash[r * 128 + ((64 + c8) ^ sw)] = lo;
            float s = sc[r];
            split4(rb[i].x * s, rb[i].y * s, rb[i].z * s, rb[i].w * s, hi, lo);
            *(uint2*)&Bsh[r * 128 + (c8 ^ sw)]        = hi;
            *(uint2*)&Bsh[r * 128 + ((64 + c8) ^ sw)] = lo;
        }
        __syncthreads();

        if (it + 1 < CTX / GKB) {
            int k0 = (it + 1) * GKB;
#pragma unroll
            for (int i = 0; i < 4; i++) {
                ra[i] = *(const float4*)&A [(size_t)(m0 + f4r[i]) * CTX + k0 + f4c[i]];
                rb[i] = *(const float4*)&Wt[(size_t)(n0 + f4r[i]) * CTX + k0 + f4c[i]];
            }
        }

        int q16 = (lane >> 4) << 4;
        bf16x8 ah[4], al[4], bx[4];
#pragma unroll
        for (int mt = 0; mt < 4; mt++) {
            int r  = wm + mt * 16 + (lane & 15);
            int sw = (r & 7) << 4;
            ah[mt] = *(const bf16x8*)&Ash[r * 128 + (q16 ^ sw)];
            al[mt] = *(const bf16x8*)&Ash[r * 128 + ((64 + q16) ^ sw)];
        }
#pragma unroll
        for (int nt = 0; nt < 4; nt++) {
            int r  = wn + nt * 16 + (lane & 15);
            int sw = (r & 7) << 4;
            bx[nt] = *(const bf16x8*)&Bsh[r * 128 + (q16 ^ sw)];
        }
#pragma unroll
        for (int mt = 0; mt < 4; mt++)
#pragma unroll
            for (int nt = 0; nt < 4; nt++)
                acc[mt][nt] = __builtin_amdgcn_mfma_f32_16x16x32_bf16(ah[mt], bx[nt], acc[mt][nt], 0, 0, 0);
#pragma unroll
        for (int mt = 0; mt < 4; mt++)
#pragma unroll
            for (int nt = 0; nt < 4; nt++)
                acc[mt][nt] = __builtin_amdgcn_mfma_f32_16x16x32_bf16(al[mt], bx[nt], acc[mt][nt], 0, 0, 0);
#pragma unroll
        for (int nt = 0; nt < 4; nt++) {
            int r  = wn + nt * 16 + (lane & 15);
            int sw = (r & 7) << 4;
            bx[nt] = *(const bf16x8*)&Bsh[r * 128 + ((64 + q16) ^ sw)];
        }
#pragma unroll
        for (int mt = 0; mt < 4; mt++)
#pragma unroll
            for (int nt = 0; nt < 4; nt++)
                acc[mt][nt] = __builtin_amdgcn_mfma_f32_16x16x32_bf16(ah[mt], bx[nt], acc[mt][nt], 0, 0, 0);
        __syncthreads();
    }

    int colbase = n0 + wn + (lane & 15);
    int rq4 = (lane >> 4) << 2;
#pragma unroll
    for (int nt = 0; nt < 4; nt++) {
        int col = colbase + nt * 16;
        float tb = trans_b[col];
#pragma unroll
        for (int mt = 0; mt < 4; mt++) {
            int m = m0 + wm + mt * 16 + rq4;
#pragma unroll
            for (int rg = 0; rg < 4; rg++)
                V[(size_t)(m + rg) * CTXM + col] = acc[mt][nt][rg] + tb;
        }
    }
}

// ---------------- Kernel 3: MFMA attention, no bulk LDS staging ----------------
// Per batch: 512 threads = 8 waves.
//  s2 = (V . w4mlu) @ Q^T  : 8 S-tiles (2 mt x 4 nt), operands built in regs from global
//  A^T[d][l] = sum_j Q[d][j] S1[l][j]     (A-op = Q natural, B-op = S1 rows)
//  Bv^T[d][l] = sum_m V[m][d] Bt[l][m]    (A-op = V cols,  B-op = Bt rows)
__global__ __launch_bounds__(512, 4)
void attn_kernel(const float* __restrict__ Ques,    // (B, 512, 50)
                 const float* __restrict__ V_mask,  // (B, 20)
                 const float* __restrict__ Q_mask,  // (B, 50)
                 const float* __restrict__ w4V,     // (512)
                 const float* __restrict__ w4Q,     // (512)
                 const float* __restrict__ w4mlu,   // (512)
                 const float* __restrict__ bias,    // (1)
                 const float* __restrict__ V,       // (B*20, 512)
                 float* __restrict__ out)           // (B, 2048, 20)
{
    __shared__ float Ssh[LC][LQ];
    __shared__ float S1f[LC][LQ];
    __shared__ float S2f[LC][LQ];
    __shared__ unsigned short S1h[LC][72];   // bf16 hi, cols 50..63 zeroed, stride 72 for banks
    __shared__ unsigned short S1l[LC][72];   // bf16 lo
    __shared__ unsigned short Bth[LC][40];   // bf16 hi, cols 20..31 zeroed
    __shared__ unsigned short Btl[LC][40];
    __shared__ float s1p[8][LQ];
    __shared__ float s0sh[LC];
    __shared__ float s1qsh[LQ];
    __shared__ float qmsh[LQ];
    __shared__ float vmsh[LC];

    int b = blockIdx.x;
    int t = threadIdx.x;
    int wid = t >> 6, lane = t & 63;
    int l15 = lane & 15;
    int kq  = (lane >> 4) << 3;   // 0,8,16,24 : 8-elem k offset
    int rq  = (lane >> 4) << 2;   // 0,4,8,12  : 4-row C offset
    const float* Qb = Ques + (size_t)b * (CTXM * LQ);
    const float* Vb = V + (size_t)b * (LC * CTXM);

    // masks
    if (t < LQ) qmsh[t] = Q_mask[(size_t)b * LQ + t];
    else if (t >= 64 && t < 64 + LC) vmsh[t - 64] = V_mask[(size_t)b * LC + (t - 64)];

    // ---- s0[l] = sum_d V[l,d] w4V[d] : coalesced row per wave + shfl reduce ----
    for (int l = wid; l < LC; l += 8) {
        float a = 0.f;
        const float* vr = Vb + (size_t)l * CTXM;
#pragma unroll
        for (int i = 0; i < CTXM / 64; i++)
            a = fmaf(vr[lane + 64 * i], w4V[lane + 64 * i], a);
#pragma unroll
        for (int o = 32; o > 0; o >>= 1) a += __shfl_xor(a, o);
        if (lane == 0) s0sh[l] = a;
    }

    // ---- s1 partials: wave w covers d in [64w, 64w+64), lane = q ----
    {
        int q = (lane < LQ) ? lane : (LQ - 1);
        float a = 0.f;
        for (int i = 0; i < 64; i++) {
            int d = (wid << 6) + i;
            a = fmaf(Qb[(size_t)d * LQ + q], w4Q[d], a);
        }
        if (lane < LQ) s1p[wid][lane] = a;
    }

    // ---- s2 via MFMA: wave tile (mt, nt) ----
    int mt = wid >> 2, nt = wid & 3;
    f32x4 accS = {0.f, 0.f, 0.f, 0.f};
    {
        int lA = mt * 16 + l15; if (lA > LC - 1) lA = LC - 1;
        int qB = nt * 16 + l15; if (qB > LQ - 1) qB = LQ - 1;
        const float* vrow = Vb + (size_t)lA * CTXM;
        for (int kt = 0; kt < 16; kt++) {
            int d0 = kt * 32 + kq;
            float xa[8], xb[8];
            float4 va = *(const float4*)&vrow[d0];
            float4 vc = *(const float4*)&vrow[d0 + 4];
            float4 wa = *(const float4*)&w4mlu[d0];
            float4 wc = *(const float4*)&w4mlu[d0 + 4];
            xa[0] = va.x * wa.x; xa[1] = va.y * wa.y; xa[2] = va.z * wa.z; xa[3] = va.w * wa.w;
            xa[4] = vc.x * wc.x; xa[5] = vc.y * wc.y; xa[6] = vc.z * wc.z; xa[7] = vc.w * wc.w;
#pragma unroll
            for (int e = 0; e < 8; e++) xb[e] = Qb[(size_t)(d0 + e) * LQ + qB];
            bf16x8 vh, vl, qh, ql;
            split8(xa, vh, vl);
            split8(xb, qh, ql);
            accS = __builtin_amdgcn_mfma_f32_16x16x32_bf16(vh, qh, accS, 0, 0, 0);
            accS = __builtin_amdgcn_mfma_f32_16x16x32_bf16(vl, qh, accS, 0, 0, 0);
            accS = __builtin_amdgcn_mfma_f32_16x16x32_bf16(vh, ql, accS, 0, 0, 0);
        }
    }
    __syncthreads();   // BAR1: s1p, s0sh, masks ready

    if (t < LQ) {
        float s = 0.f;
#pragma unroll
        for (int w = 0; w < 8; w++) s += s1p[w][t];
        s1qsh[t] = s;
    }
    __syncthreads();   // BAR2: s1qsh ready

    // ---- assemble S = s2 + s0 + s1 + bias ----
    {
        float bb = bias[0];
        int q = nt * 16 + l15;
#pragma unroll
        for (int r = 0; r < 4; r++) {
            int l = mt * 16 + rq + r;
            if (l < LC && q < LQ)
                Ssh[l][q] = accS[r] + s0sh[l] + s1qsh[q] + bb;
        }
    }
    __syncthreads();   // BAR3: Ssh ready

    // ---- row softmax (S1): wave w rows {w, w+8, w+16} ----
    for (int l = wid; l < LC; l += 8) {
        float x;
        if (lane < LQ) {
            float qm = qmsh[lane];
            x = Ssh[l][lane] * qm + (1.f - qm) * NEGV;
        } else x = -INFINITY;
        float mx = x;
#pragma unroll
        for (int o = 32; o > 0; o >>= 1) mx = fmaxf(mx, __shfl_xor(mx, o));
        float e = (lane < LQ) ? expf(x - mx) : 0.f;
        float sum = e;
#pragma unroll
        for (int o = 32; o > 0; o >>= 1) sum += __shfl_xor(sum, o);
        float p = e / sum;
        if (lane < LQ) S1f[l][lane] = p;
        // bf16 split + zero-pad cols 50..63
        uint xu = __float_as_uint(p);
        float rl = p - __uint_as_float(xu & 0xffff0000u);
        unsigned short hs = (unsigned short)(xu >> 16);
        unsigned short ls = (unsigned short)(__float_as_uint(rl) >> 16);
        S1h[l][lane] = (lane < LQ) ? hs : (unsigned short)0;
        S1l[l][lane] = (lane < LQ) ? ls : (unsigned short)0;
    }

    // ---- col softmax (S2): wave w cols 7w..7w+6 ----
    for (int ci = 0; ci < 7; ci++) {
        int c = wid * 7 + ci;
        if (c < LQ) {
            float x;
            if (lane < LC) {
                float vm = vmsh[lane];
                x = Ssh[lane][c] * vm + (1.f - vm) * NEGV;
            } else x = -INFINITY;
            float mx = x;
#pragma unroll
            for (int o = 32; o > 0; o >>= 1) mx = fmaxf(mx, __shfl_xor(mx, o));
            float e = (lane < LC) ? expf(x - mx) : 0.f;
            float sum = e;
#pragma unroll
            for (int o = 32; o > 0; o >>= 1) sum += __shfl_xor(sum, o);
            if (lane < LC) S2f[lane][c] = e / sum;
        }
    }
    __syncthreads();   // BAR4: S1f, S2f ready

    // ---- Bt[l][m] = sum_q S1[l,q] S2[m,q]; store bf16-split, zero-pad m=20..31 ----
    if (t < LC * LC) {
        int l = t % LC, m = t / LC;
        float s = 0.f;
#pragma unroll
        for (int j = 0; j < LQ; j++) s = fmaf(S1f[l][j], S2f[m][j], s);
        uint xu = __float_as_uint(s);
        float rl = s - __uint_as_float(xu & 0xffff0000u);
        Bth[l][m] = (unsigned short)(xu >> 16);
        Btl[l][m] = (unsigned short)(__float_as_uint(rl) >> 16);
    }
    if (t < 240) {      // zero pads
        int l = t % LC, m = LC + t / LC;   // m = 20..31
        Bth[l][m] = 0; Btl[l][m] = 0;
    }
    __syncthreads();   // BAR5: Bth/Btl ready

    // ---- Phase B: per d-tile (16 d's): A^T and Bv^T via MFMA + fused epilogue ----
    float* outb = out + (size_t)b * (4 * CTXM * LC);
#pragma unroll 1
    for (int i = 0; i < 4; i++) {
        int dt = wid + 8 * i;
        int d0 = dt * 16;
        // a-frags for A^T: Q rows, k = j
        int dq = d0 + l15;
        const float* qrow = Qb + (size_t)dq * LQ;
        float xa[8];
        bf16x8 qh0, ql0, qh1, ql1;
#pragma unroll
        for (int e = 0; e < 8; e++) xa[e] = qrow[kq + e];          // j <= 31 < 50
        split8(xa, qh0, ql0);
#pragma unroll
        for (int e = 0; e < 8; e++) {
            int j = 32 + kq + e;
            xa[e] = (j < LQ) ? qrow[j] : 0.f;
        }
        split8(xa, qh1, ql1);
        // a-frag for Bv^T: V columns, k = m
        float xv[8];
#pragma unroll
        for (int e = 0; e < 8; e++) {
            int m = kq + e;
            int mc = (m < LC) ? m : 0;
            float vv = Vb[(size_t)mc * CTXM + d0 + l15];
            xv[e] = (m < LC) ? vv : 0.f;
        }
        bf16x8 vth, vtl;
        split8(xv, vth, vtl);

        f32x4 accA[2] = {{0.f,0.f,0.f,0.f},{0.f,0.f,0.f,0.f}};
        f32x4 accB[2] = {{0.f,0.f,0.f,0.f},{0.f,0.f,0.f,0.f}};
#pragma unroll
        for (int n2 = 0; n2 < 2; n2++) {
            int lS = n2 * 16 + l15; if (lS > LC - 1) lS = LC - 1;
            bf16x8 s1h0 = *(const bf16x8*)&S1h[lS][kq];
            bf16x8 s1l0 = *(const bf16x8*)&S1l[lS][kq];
            bf16x8 s1h1 = *(const bf16x8*)&S1h[lS][32 + kq];
            bf16x8 s1l1 = *(const bf16x8*)&S1l[lS][32 + kq];
            accA[n2] = __builtin_amdgcn_mfma_f32_16x16x32_bf16(qh0, s1h0, accA[n2], 0, 0, 0);
            accA[n2] = __builtin_amdgcn_mfma_f32_16x16x32_bf16(ql0, s1h0, accA[n2], 0, 0, 0);
            accA[n2] = __builtin_amdgcn_mfma_f32_16x16x32_bf16(qh0, s1l0, accA[n2], 0, 0, 0);
            accA[n2] = __builtin_amdgcn_mfma_f32_16x16x32_bf16(qh1, s1h1, accA[n2], 0, 0, 0);
            accA[n2] = __builtin_amdgcn_mfma_f32_16x16x32_bf16(ql1, s1h1, accA[n2], 0, 0, 0);
            accA[n2] = __builtin_amdgcn_mfma_f32_16x16x32_bf16(qh1, s1l1, accA[n2], 0, 0, 0);
            bf16x8 bh = *(const bf16x8*)&Bth[lS][kq];
            bf16x8 bl = *(const bf16x8*)&Btl[lS][kq];
            accB[n2] = __builtin_amdgcn_mfma_f32_16x16x32_bf16(vth, bh, accB[n2], 0, 0, 0);
            accB[n2] = __builtin_amdgcn_mfma_f32_16x16x32_bf16(vtl, bh, accB[n2], 0, 0, 0);
            accB[n2] = __builtin_amdgcn_mfma_f32_16x16x32_bf16(vth, bl, accB[n2], 0, 0, 0);
        }

        // fused epilogue: coalesced stores (each 64B line fully covered)
#pragma unroll
        for (int n2 = 0; n2 < 2; n2++) {
            int l = n2 * 16 + l15;
            if (l < LC) {
#pragma unroll
                for (int r = 0; r < 4; r++) {
                    int d = d0 + rq + r;
                    float vv = Vb[(size_t)l * CTXM + d];
                    float a  = accA[n2][r];
                    float bv = accB[n2][r];
                    size_t base = (size_t)d * LC + l;
                    outb[base]                 = vv;
                    outb[base + CTXM * LC]     = a;
                    outb[base + 2 * CTXM * LC] = vv * a;
                    outb[base + 3 * CTXM * LC] = vv * bv;
                }
            }
        }
    }
}

extern "C" void kernel_launch(void* const* d_in, const int* in_sizes, int n_in,
                              void* d_out, int out_size, void* d_ws, size_t ws_size,
                              hipStream_t stream) {
    const float* Vid   = (const float*)d_in[0];
    const float* Ques  = (const float*)d_in[1];
    const float* Vmask = (const float*)d_in[2];
    const float* Qmask = (const float*)d_in[3];
    const float* tv    = (const float*)d_in[4];
    const float* tg    = (const float*)d_in[5];
    const float* tb    = (const float*)d_in[6];
    const float* w4V   = (const float*)d_in[7];
    const float* w4Q   = (const float*)d_in[8];
    const float* w4mlu = (const float*)d_in[9];
    const float* bias  = (const float*)d_in[10];
    float* out = (float*)d_out;

    float* scale = (float*)d_ws;          // 512 floats
    float* V     = scale + 512;           // 40960*512 floats (84 MB)

    scale_kernel<<<512, 256, 0, stream>>>(tv, tg, scale);
    gemm_kernel<<<1280, 256, 0, stream>>>(Vid, tv, scale, tb, V);
    attn_kernel<<<B_, 512, 0, stream>>>(Ques, Vmask, Qmask, w4V, w4Q, w4mlu, bias, V, out);
}